// Round 12
// baseline (1212.623 us; speedup 1.0000x reference)
//
#include <hip/hip_runtime.h>
#include <stdint.h>

typedef unsigned long long u64;
typedef unsigned int u32;
typedef _Float16 f16;
using i32x4  = __attribute__((ext_vector_type(4))) int;
using i32x16 = __attribute__((ext_vector_type(16))) int;
using f32x2  = __attribute__((ext_vector_type(2))) float;
using f32x4  = __attribute__((ext_vector_type(4))) float;
using f16x4  = __attribute__((ext_vector_type(4))) _Float16;
using f16x8  = __attribute__((ext_vector_type(8))) _Float16;

#define HW 16384   // 128*128

// workspace byte offsets
#define OFF_R      0ull           // f16 [16][16384 pix][64 ch] running r, PIXEL-MAJOR (33.5 MB)
#define OFF_WEFF2  35651584ull    // f32 [2 py][64 ci][4 ry][3 o][4 rx][2 px] repacked tail weights
#define OFF_SG0    67108864ull    // u64 [16][16384] sign ping (sgR)
#define OFF_SG1    69206016ull    // u64 [16][16384] sign pong (sgT)
#define OFF_NZT    71303168ull    // u64 [16][16384] (unused now)
#define OFF_WBSG   73400320ull    // i8  [33][9 tap][64 oc][64 ci] sign weights
#define OFF_ALPHA  74616832ull    // f32 [33][64]
#define OFF_WEFF   74625280ull    // f32 110592 composed tail weights

// ---------------- shared helper: expand pos/neg u64 masks to 64 i8 bytes ----------------
__device__ __forceinline__ void expand_store(signed char* dst8, u64 pos, u64 neg){
  u32 plo=(u32)pos, phi=(u32)(pos>>32), nlo=(u32)neg, nhi=(u32)(neg>>32);
  u32 tmp[16];
  #pragma unroll
  for (int i=0;i<16;i++){
    u32 np = ((i<8) ? (plo >> (4*i)) : (phi >> (4*i-32))) & 0xFu;
    u32 nm = ((i<8) ? (nlo >> (4*i)) : (nhi >> (4*i-32))) & 0xFu;
    u32 bp = (np * 0x00204081u) & 0x01010101u;
    u32 bn = (nm * 0x00204081u) & 0x01010101u;
    tmp[i] = bp | (bn * 0xFFu);
  }
  i32x4* dst = (i32x4*)dst8;
  #pragma unroll
  for (int k=0;k<4;k++){ i32x4 v; v[0]=(int)tmp[4*k]; v[1]=(int)tmp[4*k+1]; v[2]=(int)tmp[4*k+2]; v[3]=(int)tmp[4*k+3]; dst[k]=v; }
}

// ---------------- prep: i8 sign-weight tensor [conv][tap][oc][ci] + alpha ----------------
__global__ __launch_bounds__(256) void k_prep_wbsg(const float* __restrict__ wbody, const float* __restrict__ wlast,
                                                   signed char* __restrict__ wB, float* __restrict__ alpha){
  int t = blockIdx.x*256 + threadIdx.x;          // 33*9*64 = 19008
  if (t >= 33*9*64) return;
  int o = t & 63, tap = (t>>6)%9, cid = t/(64*9);
  const float* src = (cid < 32) ? (wbody + (size_t)cid*36864) : wlast;   // [o][ci][9]
  u32 d[16];
  #pragma unroll
  for (int c4=0;c4<16;c4++){
    u32 v=0;
    #pragma unroll
    for (int j=0;j<4;j++){
      float w = src[(o*64 + c4*4+j)*9 + tap];
      v |= ((w < 0.f) ? 0xFFu : 0x01u) << (8*j);
    }
    d[c4]=v;
  }
  i32x4* dst = (i32x4*)(wB + ((size_t)(cid*9+tap)*64 + o)*64);
  #pragma unroll
  for (int k=0;k<4;k++){ i32x4 v; v[0]=(int)d[4*k]; v[1]=(int)d[4*k+1]; v[2]=(int)d[4*k+2]; v[3]=(int)d[4*k+3]; dst[k]=v; }
  if (tap==0){
    float s=0.f;
    for (int ci=0;ci<64;ci++)
      #pragma unroll
      for (int tp=0;tp<9;tp++) s += fabsf(src[(o*64+ci)*9+tp]);
    alpha[cid*64+o] = s * (1.0f/576.0f);
  }
}

// ------- prep: composed up->shuffle->tail weights (9 edge variants) -------
__global__ __launch_bounds__(256) void k_prep_weff(const float* __restrict__ wup, const float* __restrict__ wtail,
                                                   float* __restrict__ weff){
  int idx = blockIdx.x*256 + threadIdx.x;     // 110592 exactly
  int rx = idx & 3;
  int px = (idx >> 2) & 1;
  int base = idx >> 3;
  int o  = base % 3;
  int t2 = base / 3;
  int ci = t2 & 63;
  int ry = (t2 >> 6) & 3;
  int py = (t2 >> 8) & 1;
  int e  = t2 >> 9;            // 0..8
  int ex = e % 3, ey = e / 3;
  int ry_off = (py - 2) + ry;
  int rx_off = (px - 2) + rx;
  float acc = 0.f;
  for (int dy=0; dy<3; dy++){
    if (ey==1 && dy==0) continue;
    if (ey==2 && dy==2) continue;
    int pydy = py + dy - 1;
    int sy = ((pydy + 4) >> 1) - 2;
    int vy = (pydy + 4) & 1;
    int a = ry_off + 1 - sy;
    if (a < 0 || a > 2) continue;
    for (int dx=0; dx<3; dx++){
      if (ex==0 && dx==0) continue;
      if (ex==2 && dx==2) continue;
      int pxdx = px + dx - 1;
      int sx = ((pxdx + 4) >> 1) - 2;
      int vx = (pxdx + 4) & 1;
      int b = rx_off + 1 - sx;
      if (b < 0 || b > 2) continue;
      for (int c=0; c<64; c++){
        int u = c*4 + vy*2 + vx;
        acc += wtail[((o*64+c)*3+dy)*3+dx] * wup[((u*64+ci)*3+a)*3+b];
      }
    }
  }
  weff[idx] = acc;
}

// ------- prep: repack interior (ex=1, ey=0) weights for packed-f32 fused tail -------
__global__ __launch_bounds__(256) void k_prep_repack(const float* __restrict__ weff, float* __restrict__ w2){
  int t = blockIdx.x*256 + threadIdx.x;     // 12288 exactly
  int px = t & 1;
  int q  = t >> 1;
  int rx = q & 3;  q >>= 2;
  int o  = q % 3;  q /= 3;
  int ry = q & 3;  q >>= 2;
  int ci = q & 63;
  int py = q >> 6;
  w2[t] = weff[(size_t)(2+py)*6144 + ry*1536 + ci*24 + (o*2+px)*4 + rx];
}

// ---------------- head: (x - shift) conv 3->64; r (f16, pixel-major) + h (f32, planar) via LDS transpose ----------------
__global__ __launch_bounds__(256) void k_head(const float* __restrict__ x, const float* __restrict__ wh,
                                              f16* __restrict__ r, float* __restrict__ h, u64* __restrict__ sgR){
  __shared__ float wl[64*27];
  __shared__ float hs[32][257];
  for (int j=threadIdx.x; j<64*27; j+=256) wl[j] = wh[j];
  const int tid = threadIdx.x;
  const int id = blockIdx.x*256 + tid;
  const int n = id >> 14, p = id & 16383;
  const int pix0 = (blockIdx.x*256) & 16383;
  const int yy = p >> 7, xx = p & 127;
  float xv[27];
  const float sh[3] = {114.444f, 111.4605f, 103.02f};
  #pragma unroll
  for (int tap=0; tap<9; tap++){
    int Yq = yy + tap/3 - 1, Xq = xx + tap%3 - 1;
    bool v = ((unsigned)Yq < 128u) && ((unsigned)Xq < 128u);
    int q = (Yq << 7) + Xq;
    #pragma unroll
    for (int c=0; c<3; c++)
      xv[c*9+tap] = v ? (x[(size_t)(n*3+c)*HW + q] - sh[c]) : 0.f;
  }
  __syncthreads();
  u64 sg = 0;
  for (int R=0; R<2; R++){
    for (int o2=0; o2<32; o2++){
      const int o = R*32 + o2;
      float acc = 0.f;
      #pragma unroll
      for (int j=0; j<27; j++) acc += wl[o*27+j] * xv[j];
      f16 rv = (f16)acc;
      sg |= (u64)((float)rv < 0.f) << o;
      hs[o2][tid] = acc;
    }
    __syncthreads();
    {
      float* hb = h + (size_t)(n*64 + R*32)*HW + pix0 + tid;
      #pragma unroll
      for (int c2=0;c2<32;c2++) hb[(size_t)c2*HW] = hs[c2][tid];
    }
    {
      f16* rb = r + ((size_t)n*HW + pix0)*64 + R*32;
      #pragma unroll
      for (int j=0;j<4;j++){
        int L = j*256 + tid;
        int pix = L >> 2, c0 = (L & 3)*8;
        f16x8 t8;
        #pragma unroll
        for (int i=0;i<8;i++) t8[i] = (f16)hs[c0+i][pix];
        *(f16x8*)(rb + (size_t)pix*64 + c0) = t8;
      }
    }
    __syncthreads();
  }
  sgR[id] = sg;
}

// ---------------- fused resblock (round-8 best config): 4-row tiles, 1024 blocks ----------------
__global__ __launch_bounds__(256) void k_rblock(const u64* __restrict__ sgIn,
                                                const signed char* __restrict__ wB1,
                                                const signed char* __restrict__ wB2,
                                                const float* __restrict__ alphaC,
                                                f16* __restrict__ rbuf,
                                                u64* __restrict__ sgOut){
  __shared__ __attribute__((aligned(16))) signed char A[46080];  // A1 [8][68]*80 (+pad); reused as A2 [6][68]*80
  __shared__ u32 sgl[6*66*2];
  __shared__ u32 nzl[6*66*2];

  const int bx  = blockIdx.x;
  const int n   = bx >> 6;
  const int rem = bx & 63;
  const int y0  = (rem >> 1) << 2;
  const int x0  = (rem & 1) << 6;

  const int lane = threadIdx.x & 63;
  const int wid  = threadIdx.x >> 6;
  const int rrow = wid >> 1;
  const int och  = wid & 1;
  const int nn   = lane & 31;
  const int q    = lane >> 5;

  // ---- stage A1: sgR rows y0-2..y0+5, cols x0-2..x0+65 ----
  for (int s = threadIdx.x; s < 8*68; s += 256){
    int g = s/68, c = s%68;
    int y = y0 - 2 + g, xc = x0 - 2 + c;
    u64 pos=0, neg=0;
    if (((unsigned)y < 128u) && ((unsigned)xc < 128u)){
      u64 sg = sgIn[(n<<14) + (y<<7) + xc];
      pos = ~sg; neg = sg;
    }
    expand_store(&A[(g*68 + c)*80], pos, neg);
  }
  __syncthreads();

  // ---- conv1: output rows y0-1+crr (crr 0..5), cols x0-1+u (u 0..65); signs/nz -> LDS ----
  {
    i32x4 Bf[9][2];
    #pragma unroll
    for (int t=0;t<9;t++)
      #pragma unroll
      for (int h=0;h<2;h++)
        Bf[t][h] = *(const i32x4*)(wB1 + ((size_t)(t*64 + och*32 + nn))*64 + h*32 + q*16);

    for (int cr2=0; cr2<3; cr2++){
      const int crr = rrow*3 + cr2;
      for (int cg=0; cg<3; cg++){
        i32x16 acc;
        #pragma unroll
        for (int k=0;k<16;k++) acc[k]=0;
        const i32x4* Ap = (const i32x4*)&A[((size_t)crr*68 + cg*32 + nn)*80 + q*16];
        #pragma unroll
        for (int dy=0;dy<3;dy++)
          #pragma unroll
          for (int dx=0;dx<3;dx++){
            const int t = dy*3+dx;
            #pragma unroll
            for (int h=0;h<2;h++){
              i32x4 a = Ap[(dy*68+dx)*5 + h*2];
              acc = __builtin_amdgcn_mfma_i32_32x32x32_i8(a, Bf[t][h], acc, 0, 0, 0);
            }
          }
        u32 sgc=0, nzc=0;
        #pragma unroll
        for (int reg=0; reg<16; reg++){
          u64 bs = __ballot(acc[reg] < 0);
          u64 bn = __ballot(acc[reg] != 0);
          const int px0 = (reg&3) + ((reg>>2)<<3);
          sgc = (lane==px0  ) ? (u32)bs       : sgc;
          sgc = (lane==px0+4) ? (u32)(bs>>32) : sgc;
          nzc = (lane==px0  ) ? (u32)bn       : nzc;
          nzc = (lane==px0+4) ? (u32)(bn>>32) : nzc;
        }
        const int u = cg*32 + lane;
        if (lane < 32 && u < 66){
          sgl[(crr*66 + u)*2 + och] = sgc;
          nzl[(crr*66 + u)*2 + och] = nzc;
        }
      }
    }
  }
  __syncthreads();

  // ---- stage A2 (in-place over A) ----
  for (int s = threadIdx.x; s < 6*66; s += 256){
    int g = s/66, c = s%66;
    int y = y0 - 1 + g, xc = x0 - 1 + c;
    u64 pos=0, neg=0;
    if (((unsigned)y < 128u) && ((unsigned)xc < 128u)){
      int e = (g*66 + c)*2;
      u64 sg = (u64)sgl[e] | ((u64)sgl[e+1] << 32);
      u64 nz = (u64)nzl[e] | ((u64)nzl[e+1] << 32);
      pos = nz & ~sg; neg = nz & sg;
    }
    expand_store(&A[(g*68 + c)*80], pos, neg);
  }
  __syncthreads();

  // ---- conv2: output rows y0+ro (ro 0..3); r RMW + sgOut ----
  {
    i32x4 Bf[9][2];
    #pragma unroll
    for (int t=0;t<9;t++)
      #pragma unroll
      for (int h=0;h<2;h++)
        Bf[t][h] = *(const i32x4*)(wB2 + ((size_t)(t*64 + och*32 + nn))*64 + h*32 + q*16);

    const float al = alphaC[och*32 + nn];

    for (int r2=0; r2<2; r2++){
      const int ro = rrow*2 + r2;
      for (int cg=0; cg<2; cg++){
        i32x16 acc;
        #pragma unroll
        for (int k=0;k<16;k++) acc[k]=0;
        const i32x4* Ap = (const i32x4*)&A[((size_t)ro*68 + cg*32 + nn)*80 + q*16];
        #pragma unroll
        for (int dy=0;dy<3;dy++)
          #pragma unroll
          for (int dx=0;dx<3;dx++){
            const int t = dy*3+dx;
            #pragma unroll
            for (int h=0;h<2;h++){
              i32x4 a = Ap[(dy*68+dx)*5 + h*2];
              acc = __builtin_amdgcn_mfma_i32_32x32x32_i8(a, Bf[t][h], acc, 0, 0, 0);
            }
          }
        const int ybase = y0 + ro, xbase = x0 + cg*32;
        float newr[16];
        f16* rp = rbuf + ((size_t)n*HW + (ybase<<7) + xbase + 4*q)*64 + och*32 + nn;
        #pragma unroll
        for (int k2=0;k2<4;k2++){
          #pragma unroll
          for (int j=0;j<4;j++){
            const int po = (8*k2 + j)*64;
            f16 old = rp[po];
            float rv = (float)old + al * (float)acc[4*k2+j];
            f16 nv = (f16)rv;
            rp[po] = nv;
            newr[4*k2+j] = (float)nv;   // sign decided on the stored f16 value
          }
        }
        u32 sgc=0;
        #pragma unroll
        for (int reg=0; reg<16; reg++){
          u64 b = __ballot(newr[reg] < 0.f);
          const int px0 = (reg&3) + ((reg>>2)<<3);
          sgc = (lane==px0  ) ? (u32)b       : sgc;
          sgc = (lane==px0+4) ? (u32)(b>>32) : sgc;
        }
        if (lane < 32){
          int p = (n<<14) + (ybase<<7) + xbase + lane;
          ((u32*)sgOut)[p*2 + och] = sgc;
        }
      }
    }
  }
}

// ---------------- last binary conv (planar res += alpha*S) ----------------
__global__ __launch_bounds__(256) void k_blast(const u64* __restrict__ sgIn,
                                               const signed char* __restrict__ wB, const float* __restrict__ alphaC,
                                               float* __restrict__ resbuf){
  __shared__ signed char Abytes[4*68*80];

  const int bx = blockIdx.x;
  const int n  = bx >> 7;
  const int rem = bx & 127;
  const int y0 = (rem >> 1) << 1;
  const int x0 = (rem & 1) << 6;

  const int lane = threadIdx.x & 63;
  const int wid  = threadIdx.x >> 6;
  const int rrow = wid >> 1;
  const int och  = wid & 1;
  const int nn   = lane & 31;
  const int q    = lane >> 5;

  i32x4 Bf[9][2];
  #pragma unroll
  for (int t=0;t<9;t++)
    #pragma unroll
    for (int h=0;h<2;h++)
      Bf[t][h] = *(const i32x4*)(wB + ((size_t)(t*64 + och*32 + nn))*64 + h*32 + q*16);

  for (int s = threadIdx.x; s < 4*66; s += 256){
    int g = s/66, c = s%66;
    int y = y0 + g - 1, xcol = x0 + c - 1;
    u64 pos=0, neg=0;
    if (((unsigned)y < 128u) && ((unsigned)xcol < 128u)){
      u64 sg = sgIn[(n<<14) + (y<<7) + xcol];
      pos = ~sg; neg = sg;
    }
    expand_store(&Abytes[(g*68 + c)*80], pos, neg);
  }
  __syncthreads();

  const float al = alphaC[och*32 + nn];

  for (int xh=0; xh<2; xh++){
    i32x16 acc;
    #pragma unroll
    for (int k=0;k<16;k++) acc[k]=0;

    const i32x4* Ap = (const i32x4*)&Abytes[(rrow*68 + xh*32 + nn)*80 + q*16];
    #pragma unroll
    for (int dy=0;dy<3;dy++)
      #pragma unroll
      for (int dx=0;dx<3;dx++){
        const int t = dy*3+dx;
        #pragma unroll
        for (int h=0;h<2;h++){
          i32x4 a = Ap[(dy*68+dx)*5 + h*2];
          acc = __builtin_amdgcn_mfma_i32_32x32x32_i8(a, Bf[t][h], acc, 0, 0, 0);
        }
      }

    const int ybase = y0 + rrow, xbase = x0 + xh*32;
    float* hp = resbuf + ((size_t)((n<<6) + och*32 + nn))*HW + (ybase<<7) + xbase;
    #pragma unroll
    for (int k2=0;k2<4;k2++){
      f32x4 hv = *(f32x4*)(hp + 4*q + 8*k2);
      #pragma unroll
      for (int j=0;j<4;j++) hv[j] += al * (float)acc[4*k2+j];
      *(f32x4*)(hp + 4*q + 8*k2) = hv;
    }
  }
}

// ---------------- fused tail v5q: quarter-grid variant (yg-split across 4 dispatches) ----------------
// Identical math to v5; grid 256 per dispatch; qy selects the yg octet.
__global__ __launch_bounds__(512) void k_tail(const float* __restrict__ res, const float* __restrict__ w2,
                                              const float* __restrict__ btail, float* __restrict__ out,
                                              int qy){
  __shared__ __attribute__((aligned(16))) char smem[26624];
  float* wsm = (float*)smem;                 // [64 ci][96] weights for this py
  f32x2* R0  = (f32x2*)smem;                 // [128][13] partials
  f32x2* R1  = ((f32x2*)smem) + 1664;        // [128][13]

  const int id  = blockIdx.x;                // 0..255
  const int xcd = id & 7;
  const int t   = id >> 3;                   // 0..31
  const int n   = xcd*2 + (t & 1);           // 2 images per XCD
  const int py  = (t >> 1) & 1;
  const int yg  = (qy << 3) + (t >> 2);      // 0..31 overall
  const int y0  = yg << 2;
  const int x   = threadIdx.x & 127;
  const int c4  = threadIdx.x >> 7;          // 0..3
  const int rbase = y0 + py - 2;             // res row window: rbase + [0..6]

  // stage weights: 6144 floats = 1536 f32x4, 512 threads x 3
  {
    const f32x4* src = (const f32x4*)(w2 + (size_t)py*6144);
    f32x4* dst = (f32x4*)wsm;
    #pragma unroll
    for (int j=0;j<3;j++) dst[threadIdx.x + 512*j] = src[threadIdx.x + 512*j];
  }

  int xo[5]; float cm[5];
  #pragma unroll
  for (int j=0;j<5;j++){
    int c = x - 2 + j;
    cm[j] = ((unsigned)c < 128u) ? 1.f : 0.f;
    xo[j] = c < 0 ? 0 : (c > 127 ? 127 : c);
  }

  float acc[4][3][2];
  #pragma unroll
  for (int k=0;k<4;k++)
    #pragma unroll
    for (int o=0;o<3;o++){ acc[k][o][0]=0.f; acc[k][o][1]=0.f; }

  __syncthreads();

  const float* rbn = res + (size_t)n*64*HW;
  const int ci0 = c4*16;
  #pragma unroll 1
  for (int ci=ci0; ci<ci0+16; ci++){
    const float* rp = rbn + (size_t)ci*HW;
    float v[7][5];
    #pragma unroll
    for (int w=0; w<7; w++){
      const int row = rbase + w;               // block-uniform -> scalar branch
      if ((unsigned)row < 128u){
        const float* q = rp + (row<<7);
        #pragma unroll
        for (int j=0;j<5;j++) v[w][j] = q[xo[j]] * cm[j];
      } else {
        #pragma unroll
        for (int j=0;j<5;j++) v[w][j] = 0.f;
      }
    }
    const float* wp = wsm + ci*96;
    #pragma unroll
    for (int ry=0; ry<4; ry++){
      const float* wr = wp + ry*24;
      f32x4 wq[6];
      #pragma unroll
      for (int jj=0;jj<6;jj++) wq[jj] = *(const f32x4*)(wr + 4*jj);
      #pragma unroll
      for (int k=0;k<4;k++){
        const float* vv = v[k+ry];
        #pragma unroll
        for (int o=0;o<3;o++){
          #pragma unroll
          for (int rx=0;rx<4;rx++){
            const int flat = o*8 + rx*2;       // [o][rx][px]
            acc[k][o][0] += wq[flat>>2][flat&3]       * vv[rx];
            acc[k][o][1] += wq[(flat+1)>>2][(flat+1)&3] * vv[rx+1];
          }
        }
      }
    }
  }

  // ---- reduction tree over c4 (wsm dead from here) ----
  __syncthreads();
  if (c4==1 || c4==3){
    f32x2* R = (c4==1) ? R0 : R1;
    #pragma unroll
    for (int k=0;k<4;k++)
      #pragma unroll
      for (int o=0;o<3;o++){
        f32x2 s; s[0]=acc[k][o][0]; s[1]=acc[k][o][1];
        R[x*13 + k*3+o] = s;
      }
  }
  __syncthreads();
  if (c4==0 || c4==2){
    f32x2* R = (c4==0) ? R0 : R1;
    #pragma unroll
    for (int k=0;k<4;k++)
      #pragma unroll
      for (int o=0;o<3;o++){
        f32x2 s = R[x*13 + k*3+o];
        acc[k][o][0] += s[0]; acc[k][o][1] += s[1];
      }
  }
  __syncthreads();
  if (c4==2){
    #pragma unroll
    for (int k=0;k<4;k++)
      #pragma unroll
      for (int o=0;o<3;o++){
        f32x2 s; s[0]=acc[k][o][0]; s[1]=acc[k][o][1];
        R0[x*13 + k*3+o] = s;
      }
  }
  __syncthreads();
  if (c4==0){
    const float sh[3] = {114.444f, 111.4605f, 103.02f};
    #pragma unroll
    for (int k=0;k<4;k++){
      const int Y = ((y0 + k) << 1) + py;
      #pragma unroll
      for (int o=0;o<3;o++){
        f32x2 s = R0[x*13 + k*3+o];
        const float b = btail[o] + sh[o];
        f32x2 s2; s2[0] = acc[k][o][0] + s[0] + b; s2[1] = acc[k][o][1] + s[1] + b;
        *(f32x2*)(out + (((size_t)((n*3+o)*256 + Y)) << 8) + 2*x) = s2;
      }
    }
  }
}

// ---------------- tail edges ----------------
__global__ __launch_bounds__(256) void k_border(const float* __restrict__ res, const float* __restrict__ weff,
                                                const float* __restrict__ btail, float* __restrict__ out){
  int t = blockIdx.x*256 + threadIdx.x;
  if (t >= 16384) return;
  int n    = t >> 10;
  int rem  = t & 1023;
  int edge = rem >> 8;
  int pos  = rem & 255;
  int X, Y;
  if (edge==0){ Y = 0;   X = pos; if (X==0 || X==255) return; }
  else if (edge==1){ Y = 255; X = pos; if (X==0 || X==255) return; }
  else if (edge==2){ X = 0;   Y = pos; }
  else            { X = 255; Y = pos; }
  int px = X & 1, x = X >> 1;
  int py = Y & 1, y = Y >> 1;
  int ey = (Y==0) ? 1 : ((Y==255) ? 2 : 0);
  int ex = (X==0) ? 0 : ((X==255) ? 2 : 1);
  const float* Ws = weff + (size_t)((ey*3+ex)*2+py) * 6144;
  float acc[3] = {0.f,0.f,0.f};
  for (int ry=0; ry<4; ry++){
    int yy = y + (py-2) + ry;
    bool rowv = ((unsigned)yy < 128u);
    const float* rp = res + (size_t)n*64*HW + yy*128;
    for (int ci=0; ci<64; ci++){
      const float* Wc = Ws + ry*1536 + ci*24 + px*4;
      #pragma unroll
      for (int rx=0; rx<4; rx++){
        int xxc = x + (px-2) + rx;
        float v = (rowv && (unsigned)xxc < 128u) ? rp[(size_t)ci*HW + xxc] : 0.f;
        acc[0] += Wc[0*8+rx] * v;
        acc[1] += Wc[1*8+rx] * v;
        acc[2] += Wc[2*8+rx] * v;
      }
    }
  }
  const float sh[3] = {114.444f, 111.4605f, 103.02f};
  for (int o=0; o<3; o++)
    out[(size_t)((n*3+o)*256+Y)*256 + X] = acc[o] + btail[o] + sh[o];
}

extern "C" void kernel_launch(void* const* d_in, const int* in_sizes, int n_in,
                              void* d_out, int out_size, void* d_ws, size_t ws_size,
                              hipStream_t stream) {
  const float* x      = (const float*)d_in[0];
  const float* w_head = (const float*)d_in[1];
  const float* w_body = (const float*)d_in[2];
  const float* w_last = (const float*)d_in[3];
  const float* w_up   = (const float*)d_in[4];
  const float* w_tail = (const float*)d_in[5];
  const float* b_tail = (const float*)d_in[6];

  char* ws = (char*)d_ws;
  f16*  r      = (f16*) (ws + OFF_R);
  u64*  sg0    = (u64*) (ws + OFF_SG0);
  u64*  sg1    = (u64*) (ws + OFF_SG1);
  signed char* wBsg = (signed char*)(ws + OFF_WBSG);
  float* alpha = (float*)(ws + OFF_ALPHA);
  float* weff  = (float*)(ws + OFF_WEFF);
  float* weff2 = (float*)(ws + OFF_WEFF2);

  float* out = (float*)d_out;        // [16,3,256,256]
  float* res = out + 3145728;        // [16,64,128,128] (holds h until last conv, then res)

  k_prep_wbsg<<<75, 256, 0, stream>>>(w_body, w_last, wBsg, alpha);
  k_prep_weff<<<432, 256, 0, stream>>>(w_up, w_tail, weff);
  k_prep_repack<<<48, 256, 0, stream>>>(weff, weff2);
  k_head<<<1024, 256, 0, stream>>>(x, w_head, r, res, sg0);

  u64* pin = sg0;
  u64* pout = sg1;
  for (int i=0; i<16; i++){
    k_rblock<<<1024, 256, 0, stream>>>(pin, wBsg + (size_t)(2*i)*36864, wBsg + (size_t)(2*i+1)*36864,
                                       alpha + (2*i+1)*64, r, pout);
    u64* tmp = pin; pin = pout; pout = tmp;
  }
  k_blast<<<2048, 256, 0, stream>>>(pin, wBsg + (size_t)32*36864, alpha + 32*64, res);

  for (int qy=0; qy<4; qy++)
    k_tail<<<256, 512, 0, stream>>>(res, weff2, b_tail, out, qy);
  k_border<<<64, 256, 0, stream>>>(res, weff, b_tail, out);
}

// Round 13
// 1116.599 us; speedup vs baseline: 1.0860x; 1.0860x over previous
//
#include <hip/hip_runtime.h>
#include <stdint.h>

typedef unsigned long long u64;
typedef unsigned int u32;
typedef _Float16 f16;
using i32x4  = __attribute__((ext_vector_type(4))) int;
using i32x16 = __attribute__((ext_vector_type(16))) int;
using f32x2  = __attribute__((ext_vector_type(2))) float;
using f32x4  = __attribute__((ext_vector_type(4))) float;
using f16x4  = __attribute__((ext_vector_type(4))) _Float16;
using f16x8  = __attribute__((ext_vector_type(8))) _Float16;

#define HW 16384   // 128*128

// workspace byte offsets
#define OFF_R      0ull           // f16 [16][16384 pix][64 ch] running r, PIXEL-MAJOR (33.5 MB)
#define OFF_WEFF2  35651584ull    // f32 [2 py][64 ci][4 ry][3 o][4 rx][2 px] repacked tail weights
#define OFF_SG0    67108864ull    // u64 [16][16384] sign ping (sgR)
#define OFF_SG1    69206016ull    // u64 [16][16384] sign pong (sgT)
#define OFF_NZT    71303168ull    // u64 [16][16384] (unused now)
#define OFF_WBSG   73400320ull    // i8  [33][9 tap][64 oc][64 ci] sign weights
#define OFF_ALPHA  74616832ull    // f32 [33][64]
#define OFF_WEFF   74625280ull    // f32 110592 composed tail weights

// ---------------- shared helper: expand pos/neg u64 masks to 64 i8 bytes ----------------
__device__ __forceinline__ void expand_store(signed char* dst8, u64 pos, u64 neg){
  u32 plo=(u32)pos, phi=(u32)(pos>>32), nlo=(u32)neg, nhi=(u32)(neg>>32);
  u32 tmp[16];
  #pragma unroll
  for (int i=0;i<16;i++){
    u32 np = ((i<8) ? (plo >> (4*i)) : (phi >> (4*i-32))) & 0xFu;
    u32 nm = ((i<8) ? (nlo >> (4*i)) : (nhi >> (4*i-32))) & 0xFu;
    u32 bp = (np * 0x00204081u) & 0x01010101u;
    u32 bn = (nm * 0x00204081u) & 0x01010101u;
    tmp[i] = bp | (bn * 0xFFu);
  }
  i32x4* dst = (i32x4*)dst8;
  #pragma unroll
  for (int k=0;k<4;k++){ i32x4 v; v[0]=(int)tmp[4*k]; v[1]=(int)tmp[4*k+1]; v[2]=(int)tmp[4*k+2]; v[3]=(int)tmp[4*k+3]; dst[k]=v; }
}

// ---------------- prep: i8 sign-weight tensor [conv][tap][oc][ci] + alpha ----------------
__global__ __launch_bounds__(256) void k_prep_wbsg(const float* __restrict__ wbody, const float* __restrict__ wlast,
                                                   signed char* __restrict__ wB, float* __restrict__ alpha){
  int t = blockIdx.x*256 + threadIdx.x;          // 33*9*64 = 19008
  if (t >= 33*9*64) return;
  int o = t & 63, tap = (t>>6)%9, cid = t/(64*9);
  const float* src = (cid < 32) ? (wbody + (size_t)cid*36864) : wlast;   // [o][ci][9]
  u32 d[16];
  #pragma unroll
  for (int c4=0;c4<16;c4++){
    u32 v=0;
    #pragma unroll
    for (int j=0;j<4;j++){
      float w = src[(o*64 + c4*4+j)*9 + tap];
      v |= ((w < 0.f) ? 0xFFu : 0x01u) << (8*j);
    }
    d[c4]=v;
  }
  i32x4* dst = (i32x4*)(wB + ((size_t)(cid*9+tap)*64 + o)*64);
  #pragma unroll
  for (int k=0;k<4;k++){ i32x4 v; v[0]=(int)d[4*k]; v[1]=(int)d[4*k+1]; v[2]=(int)d[4*k+2]; v[3]=(int)d[4*k+3]; dst[k]=v; }
  if (tap==0){
    float s=0.f;
    for (int ci=0;ci<64;ci++)
      #pragma unroll
      for (int tp=0;tp<9;tp++) s += fabsf(src[(o*64+ci)*9+tp]);
    alpha[cid*64+o] = s * (1.0f/576.0f);
  }
}

// ------- prep: composed up->shuffle->tail weights (9 edge variants) -------
__global__ __launch_bounds__(256) void k_prep_weff(const float* __restrict__ wup, const float* __restrict__ wtail,
                                                   float* __restrict__ weff){
  int idx = blockIdx.x*256 + threadIdx.x;     // 110592 exactly
  int rx = idx & 3;
  int px = (idx >> 2) & 1;
  int base = idx >> 3;
  int o  = base % 3;
  int t2 = base / 3;
  int ci = t2 & 63;
  int ry = (t2 >> 6) & 3;
  int py = (t2 >> 8) & 1;
  int e  = t2 >> 9;            // 0..8
  int ex = e % 3, ey = e / 3;
  int ry_off = (py - 2) + ry;
  int rx_off = (px - 2) + rx;
  float acc = 0.f;
  for (int dy=0; dy<3; dy++){
    if (ey==1 && dy==0) continue;
    if (ey==2 && dy==2) continue;
    int pydy = py + dy - 1;
    int sy = ((pydy + 4) >> 1) - 2;
    int vy = (pydy + 4) & 1;
    int a = ry_off + 1 - sy;
    if (a < 0 || a > 2) continue;
    for (int dx=0; dx<3; dx++){
      if (ex==0 && dx==0) continue;
      if (ex==2 && dx==2) continue;
      int pxdx = px + dx - 1;
      int sx = ((pxdx + 4) >> 1) - 2;
      int vx = (pxdx + 4) & 1;
      int b = rx_off + 1 - sx;
      if (b < 0 || b > 2) continue;
      for (int c=0; c<64; c++){
        int u = c*4 + vy*2 + vx;
        acc += wtail[((o*64+c)*3+dy)*3+dx] * wup[((u*64+ci)*3+a)*3+b];
      }
    }
  }
  weff[idx] = acc;
}

// ------- prep: repack interior (ex=1, ey=0) weights for packed-f32 fused tail -------
__global__ __launch_bounds__(256) void k_prep_repack(const float* __restrict__ weff, float* __restrict__ w2){
  int t = blockIdx.x*256 + threadIdx.x;     // 12288 exactly
  int px = t & 1;
  int q  = t >> 1;
  int rx = q & 3;  q >>= 2;
  int o  = q % 3;  q /= 3;
  int ry = q & 3;  q >>= 2;
  int ci = q & 63;
  int py = q >> 6;
  w2[t] = weff[(size_t)(2+py)*6144 + ry*1536 + ci*24 + (o*2+px)*4 + rx];
}

// ---------------- head: (x - shift) conv 3->64; r (f16, pixel-major) + h (f32, planar) via LDS transpose ----------------
__global__ __launch_bounds__(256) void k_head(const float* __restrict__ x, const float* __restrict__ wh,
                                              f16* __restrict__ r, float* __restrict__ h, u64* __restrict__ sgR){
  __shared__ float wl[64*27];
  __shared__ float hs[32][257];
  for (int j=threadIdx.x; j<64*27; j+=256) wl[j] = wh[j];
  const int tid = threadIdx.x;
  const int id = blockIdx.x*256 + tid;
  const int n = id >> 14, p = id & 16383;
  const int pix0 = (blockIdx.x*256) & 16383;
  const int yy = p >> 7, xx = p & 127;
  float xv[27];
  const float sh[3] = {114.444f, 111.4605f, 103.02f};
  #pragma unroll
  for (int tap=0; tap<9; tap++){
    int Yq = yy + tap/3 - 1, Xq = xx + tap%3 - 1;
    bool v = ((unsigned)Yq < 128u) && ((unsigned)Xq < 128u);
    int q = (Yq << 7) + Xq;
    #pragma unroll
    for (int c=0; c<3; c++)
      xv[c*9+tap] = v ? (x[(size_t)(n*3+c)*HW + q] - sh[c]) : 0.f;
  }
  __syncthreads();
  u64 sg = 0;
  for (int R=0; R<2; R++){
    for (int o2=0; o2<32; o2++){
      const int o = R*32 + o2;
      float acc = 0.f;
      #pragma unroll
      for (int j=0; j<27; j++) acc += wl[o*27+j] * xv[j];
      f16 rv = (f16)acc;
      sg |= (u64)((float)rv < 0.f) << o;
      hs[o2][tid] = acc;
    }
    __syncthreads();
    {
      float* hb = h + (size_t)(n*64 + R*32)*HW + pix0 + tid;
      #pragma unroll
      for (int c2=0;c2<32;c2++) hb[(size_t)c2*HW] = hs[c2][tid];
    }
    {
      f16* rb = r + ((size_t)n*HW + pix0)*64 + R*32;
      #pragma unroll
      for (int j=0;j<4;j++){
        int L = j*256 + tid;
        int pix = L >> 2, c0 = (L & 3)*8;
        f16x8 t8;
        #pragma unroll
        for (int i=0;i<8;i++) t8[i] = (f16)hs[c0+i][pix];
        *(f16x8*)(rb + (size_t)pix*64 + c0) = t8;
      }
    }
    __syncthreads();
  }
  sgR[id] = sg;
}

// ---------------- fused resblock (round-8 best config): 4-row tiles, 1024 blocks ----------------
__global__ __launch_bounds__(256) void k_rblock(const u64* __restrict__ sgIn,
                                                const signed char* __restrict__ wB1,
                                                const signed char* __restrict__ wB2,
                                                const float* __restrict__ alphaC,
                                                f16* __restrict__ rbuf,
                                                u64* __restrict__ sgOut){
  __shared__ __attribute__((aligned(16))) signed char A[46080];  // A1 [8][68]*80 (+pad); reused as A2 [6][68]*80
  __shared__ u32 sgl[6*66*2];
  __shared__ u32 nzl[6*66*2];

  const int bx  = blockIdx.x;
  const int n   = bx >> 6;
  const int rem = bx & 63;
  const int y0  = (rem >> 1) << 2;
  const int x0  = (rem & 1) << 6;

  const int lane = threadIdx.x & 63;
  const int wid  = threadIdx.x >> 6;
  const int rrow = wid >> 1;
  const int och  = wid & 1;
  const int nn   = lane & 31;
  const int q    = lane >> 5;

  // ---- stage A1: sgR rows y0-2..y0+5, cols x0-2..x0+65 ----
  for (int s = threadIdx.x; s < 8*68; s += 256){
    int g = s/68, c = s%68;
    int y = y0 - 2 + g, xc = x0 - 2 + c;
    u64 pos=0, neg=0;
    if (((unsigned)y < 128u) && ((unsigned)xc < 128u)){
      u64 sg = sgIn[(n<<14) + (y<<7) + xc];
      pos = ~sg; neg = sg;
    }
    expand_store(&A[(g*68 + c)*80], pos, neg);
  }
  __syncthreads();

  // ---- conv1: output rows y0-1+crr (crr 0..5), cols x0-1+u (u 0..65); signs/nz -> LDS ----
  {
    i32x4 Bf[9][2];
    #pragma unroll
    for (int t=0;t<9;t++)
      #pragma unroll
      for (int h=0;h<2;h++)
        Bf[t][h] = *(const i32x4*)(wB1 + ((size_t)(t*64 + och*32 + nn))*64 + h*32 + q*16);

    for (int cr2=0; cr2<3; cr2++){
      const int crr = rrow*3 + cr2;
      for (int cg=0; cg<3; cg++){
        i32x16 acc;
        #pragma unroll
        for (int k=0;k<16;k++) acc[k]=0;
        const i32x4* Ap = (const i32x4*)&A[((size_t)crr*68 + cg*32 + nn)*80 + q*16];
        #pragma unroll
        for (int dy=0;dy<3;dy++)
          #pragma unroll
          for (int dx=0;dx<3;dx++){
            const int t = dy*3+dx;
            #pragma unroll
            for (int h=0;h<2;h++){
              i32x4 a = Ap[(dy*68+dx)*5 + h*2];
              acc = __builtin_amdgcn_mfma_i32_32x32x32_i8(a, Bf[t][h], acc, 0, 0, 0);
            }
          }
        u32 sgc=0, nzc=0;
        #pragma unroll
        for (int reg=0; reg<16; reg++){
          u64 bs = __ballot(acc[reg] < 0);
          u64 bn = __ballot(acc[reg] != 0);
          const int px0 = (reg&3) + ((reg>>2)<<3);
          sgc = (lane==px0  ) ? (u32)bs       : sgc;
          sgc = (lane==px0+4) ? (u32)(bs>>32) : sgc;
          nzc = (lane==px0  ) ? (u32)bn       : nzc;
          nzc = (lane==px0+4) ? (u32)(bn>>32) : nzc;
        }
        const int u = cg*32 + lane;
        if (lane < 32 && u < 66){
          sgl[(crr*66 + u)*2 + och] = sgc;
          nzl[(crr*66 + u)*2 + och] = nzc;
        }
      }
    }
  }
  __syncthreads();

  // ---- stage A2 (in-place over A) ----
  for (int s = threadIdx.x; s < 6*66; s += 256){
    int g = s/66, c = s%66;
    int y = y0 - 1 + g, xc = x0 - 1 + c;
    u64 pos=0, neg=0;
    if (((unsigned)y < 128u) && ((unsigned)xc < 128u)){
      int e = (g*66 + c)*2;
      u64 sg = (u64)sgl[e] | ((u64)sgl[e+1] << 32);
      u64 nz = (u64)nzl[e] | ((u64)nzl[e+1] << 32);
      pos = nz & ~sg; neg = nz & sg;
    }
    expand_store(&A[(g*68 + c)*80], pos, neg);
  }
  __syncthreads();

  // ---- conv2: output rows y0+ro (ro 0..3); r RMW + sgOut ----
  {
    i32x4 Bf[9][2];
    #pragma unroll
    for (int t=0;t<9;t++)
      #pragma unroll
      for (int h=0;h<2;h++)
        Bf[t][h] = *(const i32x4*)(wB2 + ((size_t)(t*64 + och*32 + nn))*64 + h*32 + q*16);

    const float al = alphaC[och*32 + nn];

    for (int r2=0; r2<2; r2++){
      const int ro = rrow*2 + r2;
      for (int cg=0; cg<2; cg++){
        i32x16 acc;
        #pragma unroll
        for (int k=0;k<16;k++) acc[k]=0;
        const i32x4* Ap = (const i32x4*)&A[((size_t)ro*68 + cg*32 + nn)*80 + q*16];
        #pragma unroll
        for (int dy=0;dy<3;dy++)
          #pragma unroll
          for (int dx=0;dx<3;dx++){
            const int t = dy*3+dx;
            #pragma unroll
            for (int h=0;h<2;h++){
              i32x4 a = Ap[(dy*68+dx)*5 + h*2];
              acc = __builtin_amdgcn_mfma_i32_32x32x32_i8(a, Bf[t][h], acc, 0, 0, 0);
            }
          }
        const int ybase = y0 + ro, xbase = x0 + cg*32;
        float newr[16];
        f16* rp = rbuf + ((size_t)n*HW + (ybase<<7) + xbase + 4*q)*64 + och*32 + nn;
        #pragma unroll
        for (int k2=0;k2<4;k2++){
          #pragma unroll
          for (int j=0;j<4;j++){
            const int po = (8*k2 + j)*64;
            f16 old = rp[po];
            float rv = (float)old + al * (float)acc[4*k2+j];
            f16 nv = (f16)rv;
            rp[po] = nv;
            newr[4*k2+j] = (float)nv;   // sign decided on the stored f16 value
          }
        }
        u32 sgc=0;
        #pragma unroll
        for (int reg=0; reg<16; reg++){
          u64 b = __ballot(newr[reg] < 0.f);
          const int px0 = (reg&3) + ((reg>>2)<<3);
          sgc = (lane==px0  ) ? (u32)b       : sgc;
          sgc = (lane==px0+4) ? (u32)(b>>32) : sgc;
        }
        if (lane < 32){
          int p = (n<<14) + (ybase<<7) + xbase + lane;
          ((u32*)sgOut)[p*2 + och] = sgc;
        }
      }
    }
  }
}

// ---------------- last binary conv (planar res += alpha*S) ----------------
__global__ __launch_bounds__(256) void k_blast(const u64* __restrict__ sgIn,
                                               const signed char* __restrict__ wB, const float* __restrict__ alphaC,
                                               float* __restrict__ resbuf){
  __shared__ signed char Abytes[4*68*80];

  const int bx = blockIdx.x;
  const int n  = bx >> 7;
  const int rem = bx & 127;
  const int y0 = (rem >> 1) << 1;
  const int x0 = (rem & 1) << 6;

  const int lane = threadIdx.x & 63;
  const int wid  = threadIdx.x >> 6;
  const int rrow = wid >> 1;
  const int och  = wid & 1;
  const int nn   = lane & 31;
  const int q    = lane >> 5;

  i32x4 Bf[9][2];
  #pragma unroll
  for (int t=0;t<9;t++)
    #pragma unroll
    for (int h=0;h<2;h++)
      Bf[t][h] = *(const i32x4*)(wB + ((size_t)(t*64 + och*32 + nn))*64 + h*32 + q*16);

  for (int s = threadIdx.x; s < 4*66; s += 256){
    int g = s/66, c = s%66;
    int y = y0 + g - 1, xcol = x0 + c - 1;
    u64 pos=0, neg=0;
    if (((unsigned)y < 128u) && ((unsigned)xcol < 128u)){
      u64 sg = sgIn[(n<<14) + (y<<7) + xcol];
      pos = ~sg; neg = sg;
    }
    expand_store(&Abytes[(g*68 + c)*80], pos, neg);
  }
  __syncthreads();

  const float al = alphaC[och*32 + nn];

  for (int xh=0; xh<2; xh++){
    i32x16 acc;
    #pragma unroll
    for (int k=0;k<16;k++) acc[k]=0;

    const i32x4* Ap = (const i32x4*)&Abytes[(rrow*68 + xh*32 + nn)*80 + q*16];
    #pragma unroll
    for (int dy=0;dy<3;dy++)
      #pragma unroll
      for (int dx=0;dx<3;dx++){
        const int t = dy*3+dx;
        #pragma unroll
        for (int h=0;h<2;h++){
          i32x4 a = Ap[(dy*68+dx)*5 + h*2];
          acc = __builtin_amdgcn_mfma_i32_32x32x32_i8(a, Bf[t][h], acc, 0, 0, 0);
        }
      }

    const int ybase = y0 + rrow, xbase = x0 + xh*32;
    float* hp = resbuf + ((size_t)((n<<6) + och*32 + nn))*HW + (ybase<<7) + xbase;
    #pragma unroll
    for (int k2=0;k2<4;k2++){
      f32x4 hv = *(f32x4*)(hp + 4*q + 8*k2);
      #pragma unroll
      for (int j=0;j<4;j++) hv[j] += al * (float)acc[4*k2+j];
      *(f32x4*)(hp + 4*q + 8*k2) = hv;
    }
  }
}

// ---------------- fused tail v5: 512 threads, ci quartered, red aliased on weight LDS (26.6 KB) ----------------
__global__ __launch_bounds__(512) void k_tail(const float* __restrict__ res, const float* __restrict__ w2,
                                              const float* __restrict__ btail, float* __restrict__ out){
  __shared__ __attribute__((aligned(16))) char smem[26624];
  float* wsm = (float*)smem;                 // [64 ci][96] weights for this py
  f32x2* R0  = (f32x2*)smem;                 // [128][13] partials
  f32x2* R1  = ((f32x2*)smem) + 1664;        // [128][13]

  const int id  = blockIdx.x;
  const int xcd = id & 7;
  const int t   = id >> 3;
  const int n   = xcd*2 + (t & 1);           // 2 images per XCD
  const int py  = (t >> 1) & 1;
  const int yg  = t >> 2;                    // 0..31
  const int y0  = yg << 2;
  const int x   = threadIdx.x & 127;
  const int c4  = threadIdx.x >> 7;          // 0..3
  const int rbase = y0 + py - 2;             // res row window: rbase + [0..6]

  {
    const f32x4* src = (const f32x4*)(w2 + (size_t)py*6144);
    f32x4* dst = (f32x4*)wsm;
    #pragma unroll
    for (int j=0;j<3;j++) dst[threadIdx.x + 512*j] = src[threadIdx.x + 512*j];
  }

  int xo[5]; float cm[5];
  #pragma unroll
  for (int j=0;j<5;j++){
    int c = x - 2 + j;
    cm[j] = ((unsigned)c < 128u) ? 1.f : 0.f;
    xo[j] = c < 0 ? 0 : (c > 127 ? 127 : c);
  }

  float acc[4][3][2];
  #pragma unroll
  for (int k=0;k<4;k++)
    #pragma unroll
    for (int o=0;o<3;o++){ acc[k][o][0]=0.f; acc[k][o][1]=0.f; }

  __syncthreads();

  const float* rbn = res + (size_t)n*64*HW;
  const int ci0 = c4*16;
  #pragma unroll 1
  for (int ci=ci0; ci<ci0+16; ci++){
    const float* rp = rbn + (size_t)ci*HW;
    float v[7][5];
    #pragma unroll
    for (int w=0; w<7; w++){
      const int row = rbase + w;               // block-uniform -> scalar branch
      if ((unsigned)row < 128u){
        const float* q = rp + (row<<7);
        #pragma unroll
        for (int j=0;j<5;j++) v[w][j] = q[xo[j]] * cm[j];
      } else {
        #pragma unroll
        for (int j=0;j<5;j++) v[w][j] = 0.f;
      }
    }
    const float* wp = wsm + ci*96;
    #pragma unroll
    for (int ry=0; ry<4; ry++){
      const float* wr = wp + ry*24;
      f32x4 wq[6];
      #pragma unroll
      for (int jj=0;jj<6;jj++) wq[jj] = *(const f32x4*)(wr + 4*jj);
      #pragma unroll
      for (int k=0;k<4;k++){
        const float* vv = v[k+ry];
        #pragma unroll
        for (int o=0;o<3;o++){
          #pragma unroll
          for (int rx=0;rx<4;rx++){
            const int flat = o*8 + rx*2;       // [o][rx][px]
            acc[k][o][0] += wq[flat>>2][flat&3]       * vv[rx];
            acc[k][o][1] += wq[(flat+1)>>2][(flat+1)&3] * vv[rx+1];
          }
        }
      }
    }
  }

  // ---- reduction tree over c4 (wsm dead from here) ----
  __syncthreads();
  if (c4==1 || c4==3){
    f32x2* R = (c4==1) ? R0 : R1;
    #pragma unroll
    for (int k=0;k<4;k++)
      #pragma unroll
      for (int o=0;o<3;o++){
        f32x2 s; s[0]=acc[k][o][0]; s[1]=acc[k][o][1];
        R[x*13 + k*3+o] = s;
      }
  }
  __syncthreads();
  if (c4==0 || c4==2){
    f32x2* R = (c4==0) ? R0 : R1;
    #pragma unroll
    for (int k=0;k<4;k++)
      #pragma unroll
      for (int o=0;o<3;o++){
        f32x2 s = R[x*13 + k*3+o];
        acc[k][o][0] += s[0]; acc[k][o][1] += s[1];
      }
  }
  __syncthreads();
  if (c4==2){
    #pragma unroll
    for (int k=0;k<4;k++)
      #pragma unroll
      for (int o=0;o<3;o++){
        f32x2 s; s[0]=acc[k][o][0]; s[1]=acc[k][o][1];
        R0[x*13 + k*3+o] = s;
      }
  }
  __syncthreads();
  if (c4==0){
    const float sh[3] = {114.444f, 111.4605f, 103.02f};
    #pragma unroll
    for (int k=0;k<4;k++){
      const int Y = ((y0 + k) << 1) + py;
      #pragma unroll
      for (int o=0;o<3;o++){
        f32x2 s = R0[x*13 + k*3+o];
        const float b = btail[o] + sh[o];
        f32x2 s2; s2[0] = acc[k][o][0] + s[0] + b; s2[1] = acc[k][o][1] + s[1] + b;
        *(f32x2*)(out + (((size_t)((n*3+o)*256 + Y)) << 8) + 2*x) = s2;
      }
    }
  }
}

// ---------------- tail edges v2: 512 blocks, 32 pos x 8 ci-octets, LDS reduction ----------------
// Block = (n, edge, posgroup of 32). Thread: pl = tid&31 (position), cq = tid>>5 (ci octet, 8 ci).
// 128 loads/thread (8x fewer than v1), 8x the blocks -> latency covered by parallelism.
__global__ __launch_bounds__(256) void k_border(const float* __restrict__ res, const float* __restrict__ weff,
                                                const float* __restrict__ btail, float* __restrict__ out){
  __shared__ float part[8][32][3];
  const int b   = blockIdx.x;            // 512 = 16 n * 4 edge * 8 pg
  const int n   = b >> 5;
  const int e2  = (b >> 3) & 3;          // 0: Y=0 row, 1: Y=255 row, 2: X=0 col, 3: X=255 col
  const int pg  = b & 7;
  const int pl  = threadIdx.x & 31;
  const int cq  = threadIdx.x >> 5;      // 0..7
  const int pos = pg*32 + pl;

  int X, Y;
  bool skip;
  if (e2==0){ Y = 0;   X = pos; skip = (X==0 || X==255); }
  else if (e2==1){ Y = 255; X = pos; skip = (X==0 || X==255); }
  else if (e2==2){ X = 0;   Y = pos; skip = false; }
  else          { X = 255; Y = pos; skip = false; }

  const int px = X & 1, x = X >> 1;
  const int py = Y & 1, y = Y >> 1;
  const int ey = (Y==0) ? 1 : ((Y==255) ? 2 : 0);
  const int ex = (X==0) ? 0 : ((X==255) ? 2 : 1);
  const float* Ws = weff + (size_t)((ey*3+ex)*2+py) * 6144;

  float acc[3] = {0.f,0.f,0.f};
  const int ci0 = cq*8;
  for (int ry=0; ry<4; ry++){
    int yy = y + (py-2) + ry;
    bool rowv = ((unsigned)yy < 128u);
    const float* rp = res + (size_t)n*64*HW + yy*128;
    for (int ci=ci0; ci<ci0+8; ci++){
      const float* Wc = Ws + ry*1536 + ci*24 + px*4;
      #pragma unroll
      for (int rx=0; rx<4; rx++){
        int xxc = x + (px-2) + rx;
        float v = (rowv && (unsigned)xxc < 128u) ? rp[(size_t)ci*HW + xxc] : 0.f;
        acc[0] += Wc[0*8+rx] * v;
        acc[1] += Wc[1*8+rx] * v;
        acc[2] += Wc[2*8+rx] * v;
      }
    }
  }
  #pragma unroll
  for (int o=0;o<3;o++) part[cq][pl][o] = acc[o];
  __syncthreads();
  if (cq==0 && !skip){
    const float sh[3] = {114.444f, 111.4605f, 103.02f};
    #pragma unroll
    for (int o=0;o<3;o++){
      float s = 0.f;
      #pragma unroll
      for (int j=0;j<8;j++) s += part[j][pl][o];
      out[(size_t)((n*3+o)*256+Y)*256 + X] = s + btail[o] + sh[o];
    }
  }
}

extern "C" void kernel_launch(void* const* d_in, const int* in_sizes, int n_in,
                              void* d_out, int out_size, void* d_ws, size_t ws_size,
                              hipStream_t stream) {
  const float* x      = (const float*)d_in[0];
  const float* w_head = (const float*)d_in[1];
  const float* w_body = (const float*)d_in[2];
  const float* w_last = (const float*)d_in[3];
  const float* w_up   = (const float*)d_in[4];
  const float* w_tail = (const float*)d_in[5];
  const float* b_tail = (const float*)d_in[6];

  char* ws = (char*)d_ws;
  f16*  r      = (f16*) (ws + OFF_R);
  u64*  sg0    = (u64*) (ws + OFF_SG0);
  u64*  sg1    = (u64*) (ws + OFF_SG1);
  signed char* wBsg = (signed char*)(ws + OFF_WBSG);
  float* alpha = (float*)(ws + OFF_ALPHA);
  float* weff  = (float*)(ws + OFF_WEFF);
  float* weff2 = (float*)(ws + OFF_WEFF2);

  float* out = (float*)d_out;        // [16,3,256,256]
  float* res = out + 3145728;        // [16,64,128,128] (holds h until last conv, then res)

  k_prep_wbsg<<<75, 256, 0, stream>>>(w_body, w_last, wBsg, alpha);
  k_prep_weff<<<432, 256, 0, stream>>>(w_up, w_tail, weff);
  k_prep_repack<<<48, 256, 0, stream>>>(weff, weff2);
  k_head<<<1024, 256, 0, stream>>>(x, w_head, r, res, sg0);

  u64* pin = sg0;
  u64* pout = sg1;
  for (int i=0; i<16; i++){
    k_rblock<<<1024, 256, 0, stream>>>(pin, wBsg + (size_t)(2*i)*36864, wBsg + (size_t)(2*i+1)*36864,
                                       alpha + (2*i+1)*64, r, pout);
    u64* tmp = pin; pin = pout; pout = tmp;
  }
  k_blast<<<2048, 256, 0, stream>>>(pin, wBsg + (size_t)32*36864, alpha + 32*64, res);

  k_tail<<<1024, 512, 0, stream>>>(res, weff2, b_tail, out);
  k_border<<<512, 256, 0, stream>>>(res, weff, b_tail, out);
}